// Round 10
// baseline (3162.186 us; speedup 1.0000x reference)
//
#include <hip/hip_runtime.h>
#include <hip/hip_bf16.h>

#define Bb    128
#define Ss    256
#define Ff    4
#define Vv    1024
#define Ee    512
#define Hh    1024
#define FourH 4096
#define Mrows (Bb * Ss)
#define NBLK  192      // 64 layer-0 WGs + 128 layer-1 WGs

typedef _Float16 f16;
typedef __attribute__((ext_vector_type(8))) _Float16 half8;
typedef __attribute__((ext_vector_type(4))) float f32x4;

// ---------------------------------------------------------------------------
__global__ void cvt_f16_kernel(const float* __restrict__ s, f16* __restrict__ d, int n) {
    int i = blockIdx.x * blockDim.x + threadIdx.x;
    int stride = gridDim.x * blockDim.x;
    for (; i < n; i += stride) d[i] = (f16)s[i];
}

__global__ void bias_combine_kernel(const float* __restrict__ a, const float* __restrict__ b,
                                    const float* __restrict__ c, const float* __restrict__ d,
                                    float* __restrict__ o0, float* __restrict__ o1) {
    int i = blockIdx.x * blockDim.x + threadIdx.x;
    if (i < FourH) o0[i] = a[i] + b[i];
    else if (i < 2 * FourH) { int j = i - FourH; o1[j] = c[j] + d[j]; }
}

// Embedding: sum over F tables -> f16 [S, B, E] (time-major)
__global__ void emb_kernel(const int* __restrict__ x, const float* __restrict__ emb,
                           f16* __restrict__ out) {
    int r = blockIdx.x;
    int t = threadIdx.x;
    int b = r / Ss, s = r % Ss;
    const int* xr = x + (size_t)r * Ff;
    const float* e0 = emb + (size_t)xr[0] * Ee;
    const float* e1 = emb + (size_t)(Vv + xr[1]) * Ee;
    const float* e2 = emb + (size_t)(2 * Vv + xr[2]) * Ee;
    const float* e3 = emb + (size_t)(3 * Vv + xr[3]) * Ee;
    f16* orow = out + (size_t)(s * Bb + b) * Ee;
    for (int e = t; e < Ee; e += 256) orow[e] = (f16)(e0[e] + e1[e] + e2[e] + e3[e]);
}

// ---------------------------------------------------------------------------
// C[M,N] = A[M,K] @ B[N,K]^T + bias[N]  (f16 in, f16 out, fp32 accum)
#define BM 128
#define BN 128
#define BK 32
#define LDP 40

__global__ __launch_bounds__(256) void gemm_bt_kernel(
    const f16* __restrict__ A, const f16* __restrict__ Bw,
    const float* __restrict__ bias, f16* __restrict__ C,
    int M, int N, int K)
{
    __shared__ f16 As[BM * LDP];
    __shared__ f16 Bs[BN * LDP];
    int tid  = threadIdx.x;
    int n0   = blockIdx.x * BN;
    int m0   = blockIdx.y * BM;
    int w    = tid >> 6, lane = tid & 63;
    int wm   = (w >> 1) * 64, wn = (w & 1) * 64;
    int lrow = lane & 15, koff = lane >> 4;

    f32x4 acc[4][4] = {};

    for (int kb = 0; kb < K; kb += BK) {
        __syncthreads();
        #pragma unroll
        for (int h = 0; h < 2; ++h) {
            int ch  = tid + h * 256;
            int row = ch >> 2;
            int cc  = (ch & 3) * 8;
            *reinterpret_cast<uint4*>(&As[row * LDP + cc]) =
                *reinterpret_cast<const uint4*>(A + (size_t)(m0 + row) * K + kb + cc);
            *reinterpret_cast<uint4*>(&Bs[row * LDP + cc]) =
                *reinterpret_cast<const uint4*>(Bw + (size_t)(n0 + row) * K + kb + cc);
        }
        __syncthreads();
        half8 af[4], bf[4];
        #pragma unroll
        for (int mt = 0; mt < 4; ++mt)
            af[mt] = *reinterpret_cast<const half8*>(&As[(wm + mt * 16 + lrow) * LDP + koff * 8]);
        #pragma unroll
        for (int nt = 0; nt < 4; ++nt)
            bf[nt] = *reinterpret_cast<const half8*>(&Bs[(wn + nt * 16 + lrow) * LDP + koff * 8]);
        #pragma unroll
        for (int mt = 0; mt < 4; ++mt)
            #pragma unroll
            for (int nt = 0; nt < 4; ++nt)
                acc[mt][nt] = __builtin_amdgcn_mfma_f32_16x16x32_f16(af[mt], bf[nt], acc[mt][nt], 0, 0, 0);
    }

    #pragma unroll
    for (int mt = 0; mt < 4; ++mt)
        #pragma unroll
        for (int nt = 0; nt < 4; ++nt) {
            int col = n0 + wn + nt * 16 + lrow;
            float bv = bias[col];
            #pragma unroll
            for (int r = 0; r < 4; ++r) {
                int rowg = m0 + wm + mt * 16 + koff * 4 + r;
                C[(size_t)rowg * N + col] = (f16)(acc[mt][nt][r] + bv);
            }
        }
}

// ---------------------------------------------------------------------------
__device__ __forceinline__ void gload_lds16(const void* g, void* l) {
    __builtin_amdgcn_global_load_lds((const __attribute__((address_space(1))) void*)g,
                                     (__attribute__((address_space(3))) void*)l, 16, 0, 0);
}

// Device-coherent 4B store: write-through past L1/L2 to the coherence point
// (MALL). Visible device-wide once vmcnt retires - no wbl2 fence needed.
__device__ __forceinline__ void gst_cc(void* p, unsigned v) {
    asm volatile("global_store_dword %0, %1, off sc0 sc1" :: "v"(p), "v"(v) : "memory");
}

__device__ __forceinline__ float f16lo(unsigned u) {
    return (float)__builtin_bit_cast(f16, (unsigned short)(u & 0xffffu));
}
__device__ __forceinline__ float f16hi(unsigned u) {
    return (float)__builtin_bit_cast(f16, (unsigned short)(u >> 16));
}

__device__ __forceinline__ unsigned aload(unsigned* p) {
    return __hip_atomic_load(p, __ATOMIC_RELAXED, __HIP_MEMORY_SCOPE_AGENT);
}

// Per-wave gate: spin until counter >= target (all lanes load the same
// address -> single coalesced request; branch is wave-uniform).
__device__ __forceinline__ void wave_gate(unsigned* ctr, int target) {
    while ((int)aload(ctr) < target) __builtin_amdgcn_s_sleep(2);
}

__device__ __forceinline__ float sigm(float v) { return 1.f / (1.f + __expf(-v)); }

// ---------------------------------------------------------------------------
// Persistent fused 2-layer LSTM scan, R10: DECENTRALIZED PER-WAVE GATING.
// No release counters: consumers poll ARRIVAL counters against 32*i / 64*i
// (one MALL RTT less per handoff). Gates are per-wave: L1's h1-staging waves
// (kq>=4) gate only on their own group's counter, h0 waves (kq<4) only on
// L0's - each wave starts staging the moment its producer is done. One
// barrier point per iteration: vmcnt(0)+syncthreads+tid0 arrival; the wait
// is fused into the next iteration's gates. Periodic acquire-inv (i%8==0,
// ring depth 8 >= inv period - R9's staleness argument unchanged) keeps a
// rare WG-wide bracket. h handoff: packed sc0/sc1 write-through stores (R7).
// Counters: bar[rowg*32]=arr0 (32/iter), bar[(2+rowg)*32]=arr1 (64/iter).
__global__ __launch_bounds__(512, 2) __attribute__((amdgpu_waves_per_eu(2, 2)))
void scan_kernel(
    const f16* __restrict__ gx0,    // gates0 chunk base [nt][128][4096]
    int t_begin, int t_end,
    const f16* __restrict__ wih1, const f16* __restrict__ whh0,
    const f16* __restrict__ whh1, const float* __restrict__ bias1,
    f16* __restrict__ h0r,          // 8-slot ring [8][128][1024]
    f16* __restrict__ h1r,          // 8-slot ring [8][128][1024]
    float* __restrict__ c0, float* __restrict__ c1,
    float* __restrict__ out, unsigned* __restrict__ bar)
{
    __shared__ __align__(1024) char smem[131072];
    float* ep = (float*)smem;

    const int tid  = threadIdx.x;
    const int wg   = blockIdx.x;
    const int lane = tid & 63;
    const int w    = tid >> 6;
    const int lrow = lane & 15, koff = lane >> 4;
    const unsigned swz   = (unsigned)((lane & 7) << 4);
    const unsigned e0s   = ((unsigned)(koff * 16)) ^ swz;         // (kc&1)==0
    const unsigned e1s   = ((unsigned)(64 + koff * 16)) ^ swz;    // (kc&1)==1
    const unsigned lane16 = (unsigned)(lane << 4);
    const size_t HSLOT = (size_t)Bb * Hh;   // f16 elems per ring slot

    if (wg < 64) {
        // ---------------- Layer 0: rowg(2) x ug(32 units), waves np(4) x kh(2)
        const int rowg = wg >> 5, ug = wg & 31;
        const int np = w & 3, kh = w >> 2;
        const int u0 = ug * 32;
        const size_t growb = (size_t)rowg * 64;
        const int cw = np * 32 + lrow;         // + nt*16

        unsigned* arr0 = bar + (0 + rowg) * 32;   // L0 arrivals (this half)
        unsigned* arr1 = bar + (2 + rowg) * 32;   // L1 arrivals (read-only here)

        half8 wreg[16][2];
        #pragma unroll
        for (int kc = 0; kc < 16; ++kc)
            #pragma unroll
            for (int nt = 0; nt < 2; ++nt) {
                int c = cw + nt * 16;
                wreg[kc][nt] = *(const half8*)(whh0
                    + (size_t)((c >> 5) * Hh + u0 + (c & 31)) * Hh
                    + kh * 512 + kc * 32 + koff * 8);
            }

        float creg[2][2];
        #pragma unroll
        for (int q = 0; q < 2; ++q) {
            int p = tid + q * 512, row = p >> 4, up = p & 15;
            float2 cc = *(const float2*)&c0[(growb + row) * Hh + u0 + 2 * up];
            creg[q][0] = cc.x; creg[q][1] = cc.y;
        }

        for (int i = t_begin; i < t_end; ++i) {
            if (i < 256) {
                // per-wave data gate: h0[i-1] ready (own group past iter i-1)
                wave_gate(arr0, 32 * i);
                if ((i & 7) == 0) {                 // periodic L2 inv bracket
                    __syncthreads();
                    if (tid == 0) __builtin_amdgcn_fence(__ATOMIC_ACQUIRE, "agent");
                    __syncthreads();
                }
                const f16* hp = h0r + (size_t)((unsigned)((i - 1) & 7)) * HSLOT; // h0[i-1]
                f16*       hw = h0r + (size_t)(i & 7) * HSLOT;                   // h0[i]
                const f16* gx = gx0 + (size_t)(i - t_begin) * (Bb * FourH);
                const char* hb = (const char*)hp + growb * 2048;

                // gate-input prefetch, 2 f16 packed per gate (plain cached loads)
                unsigned gxu[2][4];
                #pragma unroll
                for (int q = 0; q < 2; ++q) {
                    int p = tid + q * 512, row = p >> 4, up = p & 15;
                    const unsigned* gr = (const unsigned*)(gx + (growb + row) * FourH + u0) + up;
                    gxu[q][0] = gr[0];
                    gxu[q][1] = gr[512];
                    gxu[q][2] = gr[1024];
                    gxu[q][3] = gr[1536];
                }

                // single-shot stage: 64 rows x 2048 B (16 instr/wave)
                #pragma unroll
                for (int t = 0; t < 16; ++t) {
                    int row  = w * 8 + (t >> 1);
                    int half = t & 1;
                    gload_lds16(hb + (size_t)row * 2048 + half * 1024
                                   + (lane16 ^ ((unsigned)((row & 7) << 4))),
                                smem + row * 2048 + half * 1024);
                }

                asm volatile("s_waitcnt vmcnt(0)" ::: "memory");
                __syncthreads();

                f32x4 acc[4][2] = {};
                #pragma unroll
                for (int kc = 0; kc < 16; ++kc) {
                    unsigned off = (unsigned)(kh * 1024 + (kc >> 1) * 128)
                                 + ((kc & 1) ? e1s : e0s);
                    half8 a[4];
                    #pragma unroll
                    for (int mt = 0; mt < 4; ++mt)
                        a[mt] = *(const half8*)(smem + (mt * 16 + lrow) * 2048 + off);
                    #pragma unroll
                    for (int mt = 0; mt < 4; ++mt) {
                        acc[mt][0] = __builtin_amdgcn_mfma_f32_16x16x32_f16(a[mt], wreg[kc][0], acc[mt][0], 0, 0, 0);
                        acc[mt][1] = __builtin_amdgcn_mfma_f32_16x16x32_f16(a[mt], wreg[kc][1], acc[mt][1], 0, 0, 0);
                    }
                }
                __syncthreads();           // staging reads done before ep overwrite
                // ep[kh][row][c] : [2][64][128]
                #pragma unroll
                for (int mt = 0; mt < 4; ++mt)
                    #pragma unroll
                    for (int nt = 0; nt < 2; ++nt) {
                        int c = cw + nt * 16;
                        int rowb = mt * 16 + koff * 4;
                        #pragma unroll
                        for (int r = 0; r < 4; ++r)
                            ep[(kh * 64 + rowb + r) * 128 + c] = acc[mt][nt][r];
                    }
                // per-wave WAR gate on h0 ring slot i&7: consumers of h0[i-8]
                // (L0 iter i-7, L1 iter i-7) must be done -> arr1 >= 64*(i-6).
                wave_gate(arr1, 64 * (i - 6));
                __syncthreads();
                #pragma unroll
                for (int q = 0; q < 2; ++q) {
                    int p = tid + q * 512, row = p >> 4, up = p & 15, uu = 2 * up;
                    float2 iP = *(const float2*)&ep[row * 128 + uu];
                    float2 iQ = *(const float2*)&ep[(64 + row) * 128 + uu];
                    float2 fP = *(const float2*)&ep[row * 128 + 32 + uu];
                    float2 fQ = *(const float2*)&ep[(64 + row) * 128 + 32 + uu];
                    float2 gP = *(const float2*)&ep[row * 128 + 64 + uu];
                    float2 gQ = *(const float2*)&ep[(64 + row) * 128 + 64 + uu];
                    float2 oP = *(const float2*)&ep[row * 128 + 96 + uu];
                    float2 oQ = *(const float2*)&ep[(64 + row) * 128 + 96 + uu];
                    float ip0 = iP.x + iQ.x + f16lo(gxu[q][0]);
                    float ip1 = iP.y + iQ.y + f16hi(gxu[q][0]);
                    float fp0 = fP.x + fQ.x + f16lo(gxu[q][1]);
                    float fp1 = fP.y + fQ.y + f16hi(gxu[q][1]);
                    float gp0 = gP.x + gQ.x + f16lo(gxu[q][2]);
                    float gp1 = gP.y + gQ.y + f16hi(gxu[q][2]);
                    float op0 = oP.x + oQ.x + f16lo(gxu[q][3]);
                    float op1 = oP.y + oQ.y + f16hi(gxu[q][3]);
                    float cn0 = sigm(fp0) * creg[q][0] + sigm(ip0) * tanhf(gp0);
                    float cn1 = sigm(fp1) * creg[q][1] + sigm(ip1) * tanhf(gp1);
                    creg[q][0] = cn0; creg[q][1] = cn1;
                    f16 hA = (f16)(sigm(op0) * tanhf(cn0));
                    f16 hB = (f16)(sigm(op1) * tanhf(cn1));
                    unsigned hv = (unsigned)__builtin_bit_cast(unsigned short, hA)
                                | ((unsigned)__builtin_bit_cast(unsigned short, hB) << 16);
                    gst_cc((void*)(hw + (growb + row) * Hh + u0 + uu), hv);
                }
            }
            // ---- end-of-iteration: drain + arrive (no wait here) ----
            asm volatile("s_waitcnt vmcnt(0)" ::: "memory");   // h0 stores at MALL
            __syncthreads();
            if (tid == 0) atomicAdd(arr0, 1u);
        }
        #pragma unroll
        for (int q = 0; q < 2; ++q) {
            int p = tid + q * 512, row = p >> 4, up = p & 15;
            *(float2*)&c0[(growb + row) * Hh + u0 + 2 * up] = make_float2(creg[q][0], creg[q][1]);
        }
    } else {
        // ---------------- Layer 1: rowg(2) x ug(64; 16 units), waves = pure kq(8)
        const int wgl = wg - 64;
        const int rowg = wgl >> 6, ug = wgl & 63;
        const int kq = w;                      // 0..7 : K-window kq*256 of 2048
        const int u0 = ug * 16;
        const size_t growb = (size_t)rowg * 64;
        const int l7 = lane & 7;

        unsigned* arr0 = bar + (0 + rowg) * 32;   // L0 arrivals (read-only here)
        unsigned* arr1 = bar + (2 + rowg) * 32;   // L1 arrivals (this half)

        const f16* wbase = (kq < 4) ? wih1 : whh1;
        half8 wreg[8][4];                      // [kc][nt], K = (kq&3)*256 + kc*32
        #pragma unroll
        for (int kc = 0; kc < 8; ++kc)
            #pragma unroll
            for (int nt = 0; nt < 4; ++nt)     // col = nt*16+lrow: gate=nt, unit=lrow
                wreg[kc][nt] = *(const half8*)(wbase
                    + (size_t)(nt * Hh + u0 + lrow) * Hh
                    + (kq & 3) * 256 + kc * 32 + koff * 8);

        const int erow = tid >> 3, eup = tid & 7, euu = 2 * eup;
        float crg0, crg1;
        { float2 cc = *(const float2*)&c1[(growb + erow) * Hh + u0 + euu];
          crg0 = cc.x; crg1 = cc.y; }
        float2 bI = *(const float2*)&bias1[u0 + euu];
        float2 bF = *(const float2*)&bias1[Hh + u0 + euu];
        float2 bG = *(const float2*)&bias1[2 * Hh + u0 + euu];
        float2 bO = *(const float2*)&bias1[3 * Hh + u0 + euu];

        const unsigned wb = (unsigned)kq * 16384u;   // this wave's 16 KB LDS slab
        const int r2 = lane >> 5;                    // 0/1 (row parity per instr)
        const int chs0 = lane & 31;                  // 16B-chunk slot in 512B row

        #define STG(rb_, bo_) { \
            _Pragma("unroll") \
            for (int t = 0; t < 8; ++t) { \
                int rl = (rb_) + t * 2 + r2; \
                gload_lds16(src + (size_t)rl * 2048 \
                                + ((unsigned)((chs0 ^ (rl & 7)) << 4)), \
                            smem + wb + (bo_) + (unsigned)(t * 1024)); \
            } }
        #define CMT(mt_, bo_) { \
            _Pragma("unroll") \
            for (int kc = 0; kc < 8; ++kc) { \
                half8 a = *(const half8*)(smem + wb + (bo_) \
                            + (unsigned)(lrow * 512) \
                            + ((unsigned)(((kc * 4 + koff) ^ l7) << 4))); \
                acc[mt_][0] = __builtin_amdgcn_mfma_f32_16x16x32_f16(a, wreg[kc][0], acc[mt_][0], 0, 0, 0); \
                acc[mt_][1] = __builtin_amdgcn_mfma_f32_16x16x32_f16(a, wreg[kc][1], acc[mt_][1], 0, 0, 0); \
                acc[mt_][2] = __builtin_amdgcn_mfma_f32_16x16x32_f16(a, wreg[kc][2], acc[mt_][2], 0, 0, 0); \
                acc[mt_][3] = __builtin_amdgcn_mfma_f32_16x16x32_f16(a, wreg[kc][3], acc[mt_][3], 0, 0, 0); \
            } }

        for (int i = t_begin; i < t_end; ++i) {
            int t1 = i - 1;
            if (t1 >= 0) {
                // per-wave data gates: h0 waves need L0 past iter i-1;
                // h1 waves need own group past iter i-1. Independent!
                if (kq < 4) wave_gate(arr0, 32 * i);
                else        wave_gate(arr1, 64 * i);
                if ((i & 7) == 0) {                 // periodic L2 inv bracket
                    __syncthreads();
                    if (tid == 0) __builtin_amdgcn_fence(__ATOMIC_ACQUIRE, "agent");
                    __syncthreads();
                }

                const f16* a0 = h0r + (size_t)(t1 & 7) * HSLOT;               // h0[t1]
                const f16* a1 = h1r + (size_t)((unsigned)((t1 - 1) & 7)) * HSLOT; // h1[t1-1]
                f16*       hw = h1r + (size_t)(t1 & 7) * HSLOT;               // h1[t1]
                const char* src = ((kq < 4) ? (const char*)a0 : (const char*)a1)
                                + growb * 2048 + (size_t)(kq & 3) * 512;

                f32x4 acc[4][4] = {};
                STG(0, 0u)
                STG(16, 8192u)
                asm volatile("s_waitcnt vmcnt(8)" ::: "memory");   // rows 0-15 in
                CMT(0, 0u)
                asm volatile("s_waitcnt lgkmcnt(0)" ::: "memory"); // buf0 reads done
                STG(32, 0u)
                asm volatile("s_waitcnt vmcnt(8)" ::: "memory");   // rows 16-31 in
                CMT(1, 8192u)
                asm volatile("s_waitcnt lgkmcnt(0)" ::: "memory"); // buf1 reads done
                STG(48, 8192u)
                asm volatile("s_waitcnt vmcnt(8)" ::: "memory");   // rows 32-47 in
                CMT(2, 0u)
                asm volatile("s_waitcnt vmcnt(0)" ::: "memory");   // rows 48-63 in
                CMT(3, 8192u)

                // ep partials into OWN slab (64 rows x 64 cols f32 = 16 KB).
                // layout: slab[row*256 + (c ^ (sw<<4))*4], sw=(row^(row>>2))&3
                #pragma unroll
                for (int mt = 0; mt < 4; ++mt)
                    #pragma unroll
                    for (int nt = 0; nt < 4; ++nt) {
                        int c = nt * 16 + lrow;
                        #pragma unroll
                        for (int r = 0; r < 4; ++r) {
                            int row = mt * 16 + koff * 4 + r;
                            int sw  = (row ^ (row >> 2)) & 3;
                            *(float*)(smem + wb + (unsigned)(row * 256)
                                      + (unsigned)((c ^ (sw << 4)) * 4)) = acc[mt][nt][r];
                        }
                    }
                __syncthreads();
                {
                    int sw = (erow ^ (erow >> 2)) & 3;
                    const char* rbase = smem + (unsigned)(erow * 256);
                    float s0x = bI.x, s0y = bI.y, s1x = bF.x, s1y = bF.y;
                    float s2x = bG.x, s2y = bG.y, s3x = bO.x, s3y = bO.y;
                    #pragma unroll
                    for (int k8 = 0; k8 < 8; ++k8) {
                        const char* base = rbase + (unsigned)k8 * 16384u;
                        float2 v0 = *(const float2*)(base + (unsigned)((( 0 + euu) ^ (sw << 4)) * 4));
                        float2 v1 = *(const float2*)(base + (unsigned)(((16 + euu) ^ (sw << 4)) * 4));
                        float2 v2 = *(const float2*)(base + (unsigned)(((32 + euu) ^ (sw << 4)) * 4));
                        float2 v3 = *(const float2*)(base + (unsigned)(((48 + euu) ^ (sw << 4)) * 4));
                        s0x += v0.x; s0y += v0.y; s1x += v1.x; s1y += v1.y;
                        s2x += v2.x; s2y += v2.y; s3x += v3.x; s3y += v3.y;
                    }
                    float cn0 = sigm(s1x) * crg0 + sigm(s0x) * tanhf(s2x); crg0 = cn0;
                    float cn1 = sigm(s1y) * crg1 + sigm(s0y) * tanhf(s2y); crg1 = cn1;
                    float hn0 = sigm(s3x) * tanhf(cn0);
                    float hn1 = sigm(s3y) * tanhf(cn1);
                    unsigned hv = (unsigned)__builtin_bit_cast(unsigned short, (f16)hn0)
                                | ((unsigned)__builtin_bit_cast(unsigned short, (f16)hn1) << 16);
                    gst_cc((void*)(hw + (growb + erow) * Hh + u0 + euu), hv);
                    *(float2*)&out[(growb + erow) * (size_t)(Ss * Hh)
                                   + (size_t)t1 * Hh + u0 + euu] = make_float2(hn0, hn1);
                }
            }
            // ---- end-of-iteration: drain + arrive (no wait here) ----
            asm volatile("s_waitcnt vmcnt(0)" ::: "memory");   // h1 stores at MALL
            __syncthreads();
            if (tid == 0) atomicAdd(arr1, 1u);
        }
        *(float2*)&c1[(growb + erow) * Hh + u0 + euu] = make_float2(crg0, crg1);
        #undef STG
        #undef CMT
    }
}

// ---------------------------------------------------------------------------
extern "C" void kernel_launch(void* const* d_in, const int* in_sizes, int n_in,
                              void* d_out, int out_size, void* d_ws, size_t ws_size,
                              hipStream_t stream) {
    const int*   x      = (const int*)  d_in[0];
    const float* emb    = (const float*)d_in[1];
    const float* proj_w = (const float*)d_in[2];
    const float* proj_b = (const float*)d_in[3];
    const float* W_ih0  = (const float*)d_in[4];
    const float* W_hh0  = (const float*)d_in[5];
    const float* b_ih0  = (const float*)d_in[6];
    const float* b_hh0  = (const float*)d_in[7];
    const float* W_ih1  = (const float*)d_in[8];
    const float* W_hh1  = (const float*)d_in[9];
    const float* b_ih1  = (const float*)d_in[10];
    const float* b_hh1  = (const float*)d_in[11];
    float* out = (float*)d_out;

    char* ws = (char*)d_ws;
    f16* emb_sum = (f16*)(ws);                               // 32 MB [S,B,E]
    f16* x_in    = (f16*)(ws + 33554432ull);                 // 32 MB [S,B,E]
    f16* gates   = (f16*)(ws + 67108864ull);                 // 128 MB (128-step chunk)
    char* wp     = ws + 201326592ull;
    f16* pw_f   = (f16*)wp; wp += (size_t)Ee * Ee * 2;
    f16* wih0_f = (f16*)wp; wp += (size_t)FourH * Ee * 2;
    f16* whh0_f = (f16*)wp; wp += (size_t)FourH * Hh * 2;
    f16* wih1_f = (f16*)wp; wp += (size_t)FourH * Hh * 2;
    f16* whh1_f = (f16*)wp; wp += (size_t)FourH * Hh * 2;
    float* bias0 = (float*)wp; wp += FourH * 4;
    float* bias1 = (float*)wp; wp += FourH * 4;
    char* zbase = wp;
    f16*   h0r = (f16*)wp;   wp += 8ull * Bb * Hh * 2;       // 8-slot h0 ring
    f16*   h1r = (f16*)wp;   wp += 8ull * Bb * Hh * 2;       // 8-slot h1 ring
    float* c0  = (float*)wp; wp += (size_t)Bb * Hh * 4;
    float* c1  = (float*)wp; wp += (size_t)Bb * Hh * 4;
    unsigned* bar = (unsigned*)wp; wp += 4096;               // arrival counters
    size_t zbytes = (size_t)(wp - zbase);

    // Prologue: converts, biases, zero state+counters
    cvt_f16_kernel<<<512, 256, 0, stream>>>(proj_w, pw_f,   Ee * Ee);
    cvt_f16_kernel<<<512, 256, 0, stream>>>(W_ih0,  wih0_f, FourH * Ee);
    cvt_f16_kernel<<<512, 256, 0, stream>>>(W_hh0,  whh0_f, FourH * Hh);
    cvt_f16_kernel<<<512, 256, 0, stream>>>(W_ih1,  wih1_f, FourH * Hh);
    cvt_f16_kernel<<<512, 256, 0, stream>>>(W_hh1,  whh1_f, FourH * Hh);
    bias_combine_kernel<<<32, 256, 0, stream>>>(b_ih0, b_hh0, b_ih1, b_hh1, bias0, bias1);
    hipMemsetAsync(zbase, 0, zbytes, stream);

    // Embedding + input projection (time-major)
    emb_kernel<<<Mrows, 256, 0, stream>>>(x, emb, emb_sum);
    gemm_bt_kernel<<<dim3(Ee / BN, Mrows / BM), 256, 0, stream>>>(
        emb_sum, pw_f, proj_b, x_in, Mrows, Ee, Ee);

    // Two half-sequence passes: gates0 GEMM chunk + cooperative scan
    const int CM = Mrows / 2;   // 16384 rows = 128 steps

    for (int half = 0; half < 2; ++half) {
        gemm_bt_kernel<<<dim3(FourH / BN, CM / BM), 256, 0, stream>>>(
            x_in + (size_t)half * CM * Ee, wih0_f, bias0, gates, CM, FourH, Ee);
        int tb = half * 128;
        int te = (half == 0) ? 128 : 257;   // second pass runs one extra L1-only iter
        const f16* gxp = gates;
        void* args[] = { (void*)&gxp, (void*)&tb, (void*)&te,
                         (void*)&wih1_f, (void*)&whh0_f, (void*)&whh1_f, (void*)&bias1,
                         (void*)&h0r, (void*)&h1r,
                         (void*)&c0, (void*)&c1, (void*)&out, (void*)&bar };
        hipLaunchCooperativeKernel((const void*)scan_kernel, dim3(NBLK), dim3(512),
                                   args, 0, stream);
    }
}